// Round 8
// baseline (319.193 us; speedup 1.0000x reference)
//
#include <hip/hip_runtime.h>
#include <hip/hip_bf16.h>

// Grouped conv2d as implicit GEMM per group:
//   out[b*64+co][h][w] = sum_{ci,kh,kw} W[b*64+co][ci][kh][kw] * x[b*64+ci][h+kh-1][w+kw-1]
// bf16 MFMA (16x16x32), fp32 accumulate.
//
// R8 changes vs R7 (af L2 traffic = 2.4GB chip-wide, ~70us/CU floor, biggest
// unaddressed term; all 4 waves load IDENTICAL af fragments):
//  - TILE_H 4->8, 512-thread 8-wave blocks, wave = one output row. Per-wave
//    compute code identical to R7 (acc stays 64 VGPR). af bytes per output
//    HALVE (same 295KB/block serves 2x outputs); halo overhead 1.55x->1.29x;
//    barriers/epilogue per output halve. Grid 4096.
//  - staging: 5 rows/thread, va/vb/vc triple ping-pong (24 floats in flight)
//    -> 2 serialized HBM rounds per phase instead of 3.
//  - LDS 43520B single buffer; 2 blocks/CU (VGPR-capped 16 waves, same as R7
//    effective residency).

typedef __bf16 bf16x8 __attribute__((ext_vector_type(8)));
typedef float  f32x4  __attribute__((ext_vector_type(4)));

#define NB 32
#define NH 256
#define NW 256
#define TILE_H 8
#define TILE_W 64
#define XROWS 10    // TILE_H + 2 (halo)
#define XCOLS 68    // TILE_W + 2, padded
#define HWSZ ((size_t)NH * NW)

// ---------------------------------------------------------------------------
// Repack weights into MFMA A-fragment order:
//   pk[((b*9+tap)*4+mt)*2+kc][lane][j]  (bf16, 16B per lane)
// value = W[b*64 + mt*16 + (lane&15)][kc*32 + (lane>>4)*8 + j][tap]
// ---------------------------------------------------------------------------
__global__ void repack_weights_kernel(const float* __restrict__ wsrc,
                                      __bf16* __restrict__ pk) {
    int t = blockIdx.x * blockDim.x + threadIdx.x;
    if (t >= NB * 9 * 4 * 2 * 64) return;
    int lane = t & 63;
    int r = t >> 6;
    int kc = r & 1;  r >>= 1;
    int mt = r & 3;  r >>= 2;
    int tap = r % 9;
    int b   = r / 9;
    int co  = b * 64 + mt * 16 + (lane & 15);
    int ci0 = kc * 32 + (lane >> 4) * 8;
    bf16x8 v;
#pragma unroll
    for (int j = 0; j < 8; ++j) {
        v[j] = (__bf16)wsrc[(co * 64 + ci0 + j) * 9 + tap];
    }
    *reinterpret_cast<bf16x8*>(pk + (size_t)t * 8) = v;
}

// ---------------------------------------------------------------------------
// Main conv kernel. Block = (group b, 8 output rows, 64 output cols), 8 waves.
// Wave wid owns output row h0+wid (all 64 co). LDS: one 32-ci half-tile
// xs[r][c][32], octet o of column c at 8*(o ^ ((c>>1)&3)). kc phases 0,1.
// ---------------------------------------------------------------------------
__launch_bounds__(512)
__global__ void conv_mfma_kernel(const float* __restrict__ x,
                                 const __bf16* __restrict__ pk,
                                 float* __restrict__ out) {
    __shared__ __align__(16) __bf16 xs[XROWS * XCOLS * 32];   // 43520 B

    // XCD-aware bijective swizzle: 4096 blocks, 8 XCDs -> 512-chunk per XCD
    const int orig = blockIdx.x;
    const int wg   = (orig & 7) * 512 + (orig >> 3);
    const int b    = wg >> 7;            // 0..31
    const int by   = (wg >> 2) & 31;     // 0..31
    const int bx   = wg & 3;             // 0..3
    const int h0   = by * TILE_H;
    const int w0   = bx * TILE_W;

    const int tid  = threadIdx.x;
    const int wid  = tid >> 6;           // 0..7
    const int lane = tid & 63;
    const int nl   = lane & 15;
    const int kgrp = lane >> 4;          // 0..3

    const __bf16* pkb = pk + (size_t)b * 9 * 4096;

    // A-fragment 4-slot ring over g = kc*9+tap (all indices compile-time).
    bf16x8 af[4][4];
    auto load_af = [&](int g) {           // g in [0,18)
        const int tap = (g >= 9) ? g - 9 : g;
        const int kc  = (g >= 9) ? 1 : 0;
        const int sl  = g & 3;
#pragma unroll
        for (int mt = 0; mt < 4; ++mt)
            af[sl][mt] = *reinterpret_cast<const bf16x8*>(
                pkb + tap * 4096 + ((mt * 2 + kc) * 64 + lane) * 8);
    };

    // prologue: issue g=0,1 now; they land under the staging latency
    load_af(0);
    load_af(1);

    f32x4 acc[4][4];   // [mt][q]
#pragma unroll
    for (int mt = 0; mt < 4; ++mt)
#pragma unroll
        for (int q = 0; q < 4; ++q)
            acc[mt][q] = (f32x4){0.f, 0.f, 0.f, 0.f};

    // staging thread constants: thread = (column c = lane, oct = wid&3,
    // row-half = wid>>2 -> rows rbase..rbase+4)
    const int c     = lane;              // 0..63 -> w = w0-1+c
    const int w     = w0 - 1 + c;
    const int wcl   = min(max(w, 0), NW - 1);
    const bool wbad = (w != wcl);
    const int oct   = wid & 3;
    const int rbase = (wid >> 2) * 5;    // 0 or 5
    const int sciw  = ((oct ^ ((c >> 1) & 3)) * 8);   // swizzled octet offset

    // halo thread constants (threads 0..79: c=64,65; 10 rows x 2 sides x 4 oct)
    const int hr    = tid >> 3;              // 0..9
    const int hside = (tid >> 2) & 1;        // 0,1 -> c = 64,65
    const int hoct  = tid & 3;               // local ci octet
    const int hch   = 64 + hside;
    const int hw    = w0 + 63 + hside;
    const int hwc   = min(hw, NW - 1);

#pragma unroll
    for (int kc = 0; kc < 2; ++kc) {
        // ---- stage phase kc: 32 ci, coalesced scalar loads, b128 swizzled writes ----
        {
            const int cibase = b * 64 + kc * 32 + oct * 8;
            const float* colp = x + (size_t)cibase * HWSZ + wcl;

            // halo loads first (threads 0..79), store at end
            float hv[8];
            if (tid < 80) {
                const int h  = h0 - 1 + hr;
                const int hc = min(max(h, 0), NH - 1);
                const float* src = x + ((size_t)(b * 64 + kc * 32 + hoct * 8) * NH + hc) * NW + hwc;
#pragma unroll
                for (int j = 0; j < 8; ++j) hv[j] = src[j * HWSZ];
                if (h != hc || hw != hwc) {
#pragma unroll
                    for (int j = 0; j < 8; ++j) hv[j] = 0.f;
                }
            }

            float va[8], vb[8], vc[8];
            auto load8 = [&](int r, float* v) {   // r = local row 0..4
                const int h  = h0 - 1 + rbase + r;
                const int hc = min(max(h, 0), NH - 1);
                const float* src = colp + (size_t)hc * NW;
#pragma unroll
                for (int j = 0; j < 8; ++j) v[j] = src[j * HWSZ];
                if (wbad || h != hc) {
#pragma unroll
                    for (int j = 0; j < 8; ++j) v[j] = 0.f;
                }
            };
            auto store8 = [&](int r, const float* v) {
                const int rr = rbase + r;
                bf16x8 o;
#pragma unroll
                for (int j = 0; j < 8; ++j) o[j] = (__bf16)v[j];
                *reinterpret_cast<bf16x8*>(xs + (rr * XCOLS + c) * 32 + sciw) = o;
            };

            // triple ping-pong: 3 load8s in flight -> 2 serialized HBM rounds
            load8(0, va);
            load8(1, vb);
            load8(2, vc);
            store8(0, va); load8(3, va);
            store8(1, vb); load8(4, vb);
            store8(2, vc);
            store8(3, va);
            store8(4, vb);

            if (tid < 80) {
                bf16x8 o;
#pragma unroll
                for (int j = 0; j < 8; ++j) o[j] = (__bf16)hv[j];
                // slot(64)=slot(65)=0 -> octet position = hoct
                *reinterpret_cast<bf16x8*>(xs + (hr * XCOLS + hch) * 32 + hoct * 8) = o;
            }
        }
        __syncthreads();

        // ---- compute phase kc: 9 taps, K=32 slice per tap; af ring depth-2 ----
#pragma unroll
        for (int tap = 0; tap < 9; ++tap) {
            const int g = kc * 9 + tap;
            if (g + 2 < 18) load_af(g + 2);    // depth-2 prefetch
            const int kh = tap / 3;
            const int kw = tap - kh * 3;
            const int rowbase = (wid + kh) * XCOLS;
            const int fs = g & 3;
#pragma unroll
            for (int q = 0; q < 4; ++q) {
                const int cc   = q * 16 + nl + kw;          // 0..65
                const int slot = (cc >> 1) & 3;
                bf16x8 bfv = *reinterpret_cast<const bf16x8*>(
                    xs + (rowbase + cc) * 32 + ((kgrp ^ slot) * 8));
#pragma unroll
                for (int mt = 0; mt < 4; ++mt)
                    acc[mt][q] = __builtin_amdgcn_mfma_f32_16x16x32_bf16(
                        af[fs][mt], bfv, acc[mt][q], 0, 0, 0);
            }
        }
        if (kc == 0) __syncthreads();   // protect xs before phase-1 overwrite
    }

    // ---- epilogue: D lane layout col=lane&15, row=(lane>>4)*4+reg ----
    const int mrow = kgrp * 4;
    const int h = h0 + wid;
#pragma unroll
    for (int mt = 0; mt < 4; ++mt) {
#pragma unroll
        for (int q = 0; q < 4; ++q) {
            const int ww = w0 + q * 16 + nl;
#pragma unroll
            for (int rg = 0; rg < 4; ++rg) {
                const int co = mt * 16 + mrow + rg;
                out[((size_t)(b * 64 + co) * NH + h) * NW + ww] = acc[mt][q][rg];
            }
        }
    }
}

extern "C" void kernel_launch(void* const* d_in, const int* in_sizes, int n_in,
                              void* d_out, int out_size, void* d_ws, size_t ws_size,
                              hipStream_t stream) {
    const float* x = (const float*)d_in[0];     // [1, 32*64, 256, 256] fp32
    const float* w = (const float*)d_in[1];     // [2048, 64, 3, 3] fp32
    float* out = (float*)d_out;                 // [1, 2048, 256, 256] fp32
    __bf16* pk = (__bf16*)d_ws;                 // 2.25 MB repacked bf16 weights

    {
        int total = NB * 9 * 4 * 2 * 64;        // 147456
        int blk = 256;
        int grid = (total + blk - 1) / blk;     // 576
        hipLaunchKernelGGL(repack_weights_kernel, dim3(grid), dim3(blk), 0, stream,
                           w, pk);
    }
    {
        dim3 grid(4096);                        // 1D, swizzled in-kernel
        hipLaunchKernelGGL(conv_mfma_kernel, grid, dim3(512), 0, stream,
                           x, pk, out);
    }
}